// Round 5
// baseline (4216.138 us; speedup 1.0000x reference)
//
#include <hip/hip_runtime.h>
#include <math.h>

#define N_CTX 4096
#define DIM 512
#define NPERS 16
#define KTOT (NPERS * DIM)   // 8192
#define EPS_NN 0.1f
#define TOPK_K 30

#define BM 128
#define KC 32
#define LDP (BM + 4)         // padded LDS row length (f32)
#define NSTEP (KTOT / KC)    // 256

// ---------------------------------------------------------------------------
// Kernel 1: invr[p][n] = 0.25 / max(||context[n] * weight[p]||, 1e-12)
// UNCHANGED from R2 (bit-identical invr required).
// ---------------------------------------------------------------------------
__global__ __launch_bounds__(256) void norms_kernel(
    const float* __restrict__ ctx, const float* __restrict__ w,
    float* __restrict__ invr) {
  int wid = threadIdx.x >> 6;
  int lane = threadIdx.x & 63;
  int gid = blockIdx.x * 4 + wid;          // 0 .. 65535
  int p = gid >> 12;
  int n = gid & (N_CTX - 1);
  const float4* c4 = reinterpret_cast<const float4*>(ctx + (size_t)n * DIM + lane * 8);
  const float4* w4 = reinterpret_cast<const float4*>(w + (size_t)p * DIM + lane * 8);
  float4 c0 = c4[0], c1 = c4[1];
  float4 w0 = w4[0], w1 = w4[1];
  float s = 0.f, v;
  v = c0.x * w0.x; s = fmaf(v, v, s);
  v = c0.y * w0.y; s = fmaf(v, v, s);
  v = c0.z * w0.z; s = fmaf(v, v, s);
  v = c0.w * w0.w; s = fmaf(v, v, s);
  v = c1.x * w1.x; s = fmaf(v, v, s);
  v = c1.y * w1.y; s = fmaf(v, v, s);
  v = c1.z * w1.z; s = fmaf(v, v, s);
  v = c1.w * w1.w; s = fmaf(v, v, s);
#pragma unroll
  for (int off = 32; off; off >>= 1) s += __shfl_down(s, off, 64);
  if (lane == 0) invr[(size_t)p * N_CTX + n] = 0.25f / fmaxf(sqrtf(s), 1e-12f);
}

// ---------------------------------------------------------------------------
// Kernel 2: fp32 VALU GEMM, BIT-IDENTICAL numerics to the R2 passing kernel:
//  - staging value = (a*w)*sA : two RNE muls (no contraction possible)
//  - each acc[i][j] accumulates k = 0..8191 strictly ascending via fmaf
// Optimized structure: triangular 528-block grid, KC=32, padded LDS,
// register prefetch of next step's global loads, 2 blocks/CU.
// ---------------------------------------------------------------------------
__global__ __launch_bounds__(256, 2) void att_gemm(
    const float* __restrict__ ctx, const float* __restrict__ w,
    const float* __restrict__ invr, float* __restrict__ out) {
  // triangular unmap: bid -> (by, bx), by <= bx, 32x32 upper triangle
  int bid = blockIdx.x;
  int by = 0;
  while (bid >= (by + 1) * 32 - ((by + 1) * by) / 2) ++by;
  const int bx = by + (bid - (by * 32 - (by * (by - 1)) / 2));

  __shared__ __align__(16) float As[KC][LDP];
  __shared__ __align__(16) float Bs[KC][LDP];

  const int t = threadIdx.x;
  const int tx = t & 15, ty = t >> 4;
  const int tx8 = tx * 8, ty8 = ty * 8;
  const int Ro = by * BM, Co = bx * BM;

  const int srow = t >> 1;                  // staged row 0..127
  const int sh16 = (t & 1) * 16;            // k-offset within the 32-k step

  float acc[8][8];
#pragma unroll
  for (int i = 0; i < 8; ++i)
#pragma unroll
    for (int j = 0; j < 8; ++j) acc[i][j] = 0.f;

  // prefetch registers for one staging step (16 f32 each from A-row, B-row, W)
  float4 pa[4], pb[4], pw[4];
  float psA, psB;

  {  // prologue: load step 0
    const int dk = sh16;                    // k0=0 -> p=0, dbase=0
    const float* wrow = w + dk;
    const float* arow = ctx + (size_t)(Ro + srow) * DIM + dk;
    const float* brow = ctx + (size_t)(Co + srow) * DIM + dk;
#pragma unroll
    for (int q = 0; q < 4; ++q) {
      pw[q] = *reinterpret_cast<const float4*>(wrow + 4 * q);
      pa[q] = *reinterpret_cast<const float4*>(arow + 4 * q);
      pb[q] = *reinterpret_cast<const float4*>(brow + 4 * q);
    }
    psA = invr[Ro + srow];
    psB = invr[Co + srow];
  }

  for (int s = 0; s < NSTEP; ++s) {
    __syncthreads();   // all waves done reading LDS from previous step

    // store current step's staged values (exact R2 arithmetic: (a*w)*s)
#pragma unroll
    for (int q = 0; q < 4; ++q) {
      const int kb = sh16 + 4 * q;
      As[kb + 0][srow] = (pa[q].x * pw[q].x) * psA;
      As[kb + 1][srow] = (pa[q].y * pw[q].y) * psA;
      As[kb + 2][srow] = (pa[q].z * pw[q].z) * psA;
      As[kb + 3][srow] = (pa[q].w * pw[q].w) * psA;
      Bs[kb + 0][srow] = (pb[q].x * pw[q].x) * psB;
      Bs[kb + 1][srow] = (pb[q].y * pw[q].y) * psB;
      Bs[kb + 2][srow] = (pb[q].z * pw[q].z) * psB;
      Bs[kb + 3][srow] = (pb[q].w * pw[q].w) * psB;
    }

    // issue next step's global loads (latency hides under this step's compute)
    if (s + 1 < NSTEP) {
      const int k0 = (s + 1) * KC;
      const int p = k0 >> 9;
      const int dk = (k0 & (DIM - 1)) + sh16;
      const float* wrow = w + (size_t)p * DIM + dk;
      const float* arow = ctx + (size_t)(Ro + srow) * DIM + dk;
      const float* brow = ctx + (size_t)(Co + srow) * DIM + dk;
#pragma unroll
      for (int q = 0; q < 4; ++q) {
        pw[q] = *reinterpret_cast<const float4*>(wrow + 4 * q);
        pa[q] = *reinterpret_cast<const float4*>(arow + 4 * q);
        pb[q] = *reinterpret_cast<const float4*>(brow + 4 * q);
      }
      psA = invr[(size_t)p * N_CTX + Ro + srow];
      psB = invr[(size_t)p * N_CTX + Co + srow];
    }

    __syncthreads();   // staged data visible

#pragma unroll
    for (int kk = 0; kk < KC; ++kk) {
      const float4 a0 = *reinterpret_cast<const float4*>(&As[kk][ty8]);
      const float4 a1 = *reinterpret_cast<const float4*>(&As[kk][ty8 + 4]);
      const float4 b0 = *reinterpret_cast<const float4*>(&Bs[kk][tx8]);
      const float4 b1 = *reinterpret_cast<const float4*>(&Bs[kk][tx8 + 4]);
      const float av[8] = {a0.x, a0.y, a0.z, a0.w, a1.x, a1.y, a1.z, a1.w};
      const float bv[8] = {b0.x, b0.y, b0.z, b0.w, b1.x, b1.y, b1.z, b1.w};
#pragma unroll
      for (int i = 0; i < 8; ++i)
#pragma unroll
        for (int j = 0; j < 8; ++j) acc[i][j] = fmaf(av[i], bv[j], acc[i][j]);
    }
  }

  // epilogue (same as R2): straight tile + mirrored tile
#pragma unroll
  for (int i = 0; i < 8; ++i) {
    size_t base = (size_t)(Ro + ty8 + i) * N_CTX + Co + tx8;
    *reinterpret_cast<float4*>(out + base) =
        make_float4(acc[i][0], acc[i][1], acc[i][2], acc[i][3]);
    *reinterpret_cast<float4*>(out + base + 4) =
        make_float4(acc[i][4], acc[i][5], acc[i][6], acc[i][7]);
  }
  if (bx != by) {
#pragma unroll
    for (int j = 0; j < 8; ++j) {
      size_t base = (size_t)(Co + tx8 + j) * N_CTX + Ro + ty8;
      *reinterpret_cast<float4*>(out + base) =
          make_float4(acc[0][j], acc[1][j], acc[2][j], acc[3][j]);
      *reinterpret_cast<float4*>(out + base + 4) =
          make_float4(acc[4][j], acc[5][j], acc[6][j], acc[7][j]);
    }
  }
}

// ---------------------------------------------------------------------------
// Kernel 3: per-row epsilon threshold + exact top-30 mask. UNCHANGED from R2.
// ---------------------------------------------------------------------------
__global__ __launch_bounds__(256) void topk_kernel(float* __restrict__ att) {
  __shared__ unsigned red[4];
  __shared__ unsigned eqcnt[256];

  const int n = blockIdx.x;
  const int t = threadIdx.x;
  const int wid = t >> 6, lane = t & 63;
  float* row = att + (size_t)n * N_CTX;

  float vr[16];
  unsigned ur[16];
#pragma unroll
  for (int i = 0; i < 4; ++i) {
    float4 v4 = *reinterpret_cast<const float4*>(row + t * 16 + i * 4);
    float tmp[4] = {v4.x, v4.y, v4.z, v4.w};
#pragma unroll
    for (int j = 0; j < 4; ++j) {
      float v = tmp[j];
      v = (v > EPS_NN) ? v : 0.0f;
      vr[i * 4 + j] = v;
      ur[i * 4 + j] = __float_as_uint(v);
    }
  }

  unsigned lo = 0u, hi = 0x7F800000u;
  while (lo < hi) {
    unsigned mid = lo + ((hi - lo) >> 1);
    unsigned c = 0;
#pragma unroll
    for (int i = 0; i < 16; ++i) c += (ur[i] > mid) ? 1u : 0u;
#pragma unroll
    for (int off = 32; off; off >>= 1) c += __shfl_down(c, off, 64);
    if (lane == 0) red[wid] = c;
    __syncthreads();
    unsigned tot = red[0] + red[1] + red[2] + red[3];
    __syncthreads();
    if (tot < TOPK_K) hi = mid; else lo = mid + 1;
  }
  const unsigned kbits = lo;

  {
    unsigned c = 0;
#pragma unroll
    for (int i = 0; i < 16; ++i) c += (ur[i] > kbits) ? 1u : 0u;
#pragma unroll
    for (int off = 32; off; off >>= 1) c += __shfl_down(c, off, 64);
    if (lane == 0) red[wid] = c;
  }
  __syncthreads();
  const unsigned gt = red[0] + red[1] + red[2] + red[3];
  const unsigned r_eq = TOPK_K - gt;
  __syncthreads();

  unsigned ec = 0;
#pragma unroll
  for (int i = 0; i < 16; ++i) ec += (ur[i] == kbits) ? 1u : 0u;
  eqcnt[t] = ec;
  __syncthreads();
  for (int off = 1; off < 256; off <<= 1) {
    unsigned v = eqcnt[t];
    unsigned add = (t >= off) ? eqcnt[t - off] : 0u;
    __syncthreads();
    eqcnt[t] = v + add;
    __syncthreads();
  }
  const unsigned prefix = eqcnt[t] - ec;

  unsigned seen = 0;
#pragma unroll
  for (int i = 0; i < 16; ++i) {
    float o = 0.0f;
    if (ur[i] > kbits) {
      o = vr[i];
    } else if (kbits != 0u && ur[i] == kbits) {
      if (prefix + seen < r_eq) o = vr[i];
      ++seen;
    }
    vr[i] = o;
  }
#pragma unroll
  for (int i = 0; i < 4; ++i) {
    *reinterpret_cast<float4*>(row + t * 16 + i * 4) =
        make_float4(vr[i * 4], vr[i * 4 + 1], vr[i * 4 + 2], vr[i * 4 + 3]);
  }
}

// ---------------------------------------------------------------------------
extern "C" void kernel_launch(void* const* d_in, const int* in_sizes, int n_in,
                              void* d_out, int out_size, void* d_ws, size_t ws_size,
                              hipStream_t stream) {
  const float* ctx = (const float*)d_in[0];   // (4096, 512)
  const float* w   = (const float*)d_in[1];   // (16, 512)
  float* out = (float*)d_out;                 // (4096, 4096)
  float* invr = (float*)d_ws;                 // 16*4096 f32 = 256 KB scratch

  norms_kernel<<<(NPERS * N_CTX) / 4, 256, 0, stream>>>(ctx, w, invr);

  att_gemm<<<528, 256, 0, stream>>>(ctx, w, invr, out);   // triangular grid

  topk_kernel<<<N_CTX, 256, 0, stream>>>(out);
}

// Round 7
// 2501.878 us; speedup vs baseline: 1.6852x; 1.6852x over previous
//
#include <hip/hip_runtime.h>
#include <math.h>

#define N_CTX 4096
#define DIM 512
#define NPERS 16
#define KTOT (NPERS * DIM)   // 8192
#define EPS_NN 0.1f
#define TOPK_K 30

#define BM 128
#define KC 32
#define LDW 140              // swizzled LDS row width (f32): 128 data + 12 max shift
#define NSTEP (KTOT / KC)    // 256

// column swizzle: matrix-row c lives at f32 offset c + 4*(c>>5) within the row
// range: swc(127) = 139 < LDW = 140
__device__ __forceinline__ int swc(int c) { return c + ((c >> 5) << 2); }

// ---------------------------------------------------------------------------
// Kernel 1: invr[p][n] = 0.25 / max(||context[n] * weight[p]||, 1e-12)
// UNCHANGED (bit-identical invr required).
// ---------------------------------------------------------------------------
__global__ __launch_bounds__(256) void norms_kernel(
    const float* __restrict__ ctx, const float* __restrict__ w,
    float* __restrict__ invr) {
  int wid = threadIdx.x >> 6;
  int lane = threadIdx.x & 63;
  int gid = blockIdx.x * 4 + wid;          // 0 .. 65535
  int p = gid >> 12;
  int n = gid & (N_CTX - 1);
  const float4* c4 = reinterpret_cast<const float4*>(ctx + (size_t)n * DIM + lane * 8);
  const float4* w4 = reinterpret_cast<const float4*>(w + (size_t)p * DIM + lane * 8);
  float4 c0 = c4[0], c1 = c4[1];
  float4 w0 = w4[0], w1 = w4[1];
  float s = 0.f, v;
  v = c0.x * w0.x; s = fmaf(v, v, s);
  v = c0.y * w0.y; s = fmaf(v, v, s);
  v = c0.z * w0.z; s = fmaf(v, v, s);
  v = c0.w * w0.w; s = fmaf(v, v, s);
  v = c1.x * w1.x; s = fmaf(v, v, s);
  v = c1.y * w1.y; s = fmaf(v, v, s);
  v = c1.z * w1.z; s = fmaf(v, v, s);
  v = c1.w * w1.w; s = fmaf(v, v, s);
#pragma unroll
  for (int off = 32; off; off >>= 1) s += __shfl_down(s, off, 64);
  if (lane == 0) invr[(size_t)p * N_CTX + n] = 0.25f / fmaxf(sqrtf(s), 1e-12f);
}

// ---------------------------------------------------------------------------
// Kernel 2: fp32 VALU GEMM, BIT-IDENTICAL numerics to the R2/R5 passing runs:
//  - staged value = (a*w)*s  (two RNE muls)
//  - every acc element accumulates k = 0..8191 strictly ascending via fmaf
// Structure: triangular 528-block grid, KC=32, swizzled conflict-free LDS
// (LDW=140 — R6's 136 overflowed: swc(127)=139), chunked staging.
// ---------------------------------------------------------------------------
__global__ __launch_bounds__(256) void att_gemm(
    const float* __restrict__ ctx, const float* __restrict__ w,
    const float* __restrict__ invr, float* __restrict__ out) {
  // triangular unmap: bid -> (by, bx), by <= bx
  int bid = blockIdx.x;
  int by = 0;
  while (bid >= (by + 1) * 32 - ((by + 1) * by) / 2) ++by;
  const int bx = by + (bid - (by * 32 - (by * (by - 1)) / 2));

  __shared__ __align__(16) float As[KC * LDW];
  __shared__ __align__(16) float Bs[KC * LDW];

  const int t = threadIdx.x;
  const int tx = t & 15, ty = t >> 4;
  const int tx8 = tx * 8, ty8 = ty * 8;
  const int aoff = swc(ty8);               // A-frag read base (const per thread)
  const int boff = swc(tx8);               // B-frag read base
  const int Ro = by * BM, Co = bx * BM;

  const int srow = t >> 1;                  // staged matrix-row 0..127
  const int sh16 = (t & 1) * 16;            // k-offset within the 32-k step
  const int scol = swc(srow);               // staged LDS column (swizzled)

  float acc[8][8];
#pragma unroll
  for (int i = 0; i < 8; ++i)
#pragma unroll
    for (int j = 0; j < 8; ++j) acc[i][j] = 0.f;

  for (int s = 0; s < NSTEP; ++s) {
    const int k0 = s * KC;
    const int p = k0 >> 9;
    const int dk = (k0 & (DIM - 1)) + sh16;
    const float* wrow = w + (size_t)p * DIM + dk;
    const float* arow = ctx + (size_t)(Ro + srow) * DIM + dk;
    const float* brow = ctx + (size_t)(Co + srow) * DIM + dk;

    // first half-chunk loads issue before the barrier (latency overlaps wait)
    float4 wv0 = *reinterpret_cast<const float4*>(wrow);
    float4 wv1 = *reinterpret_cast<const float4*>(wrow + 4);
    float4 av0 = *reinterpret_cast<const float4*>(arow);
    float4 av1 = *reinterpret_cast<const float4*>(arow + 4);
    float4 bv0 = *reinterpret_cast<const float4*>(brow);
    float4 bv1 = *reinterpret_cast<const float4*>(brow + 4);
    const float sA = invr[(size_t)p * N_CTX + Ro + srow];
    const float sB = invr[(size_t)p * N_CTX + Co + srow];

    __syncthreads();   // all waves done reading LDS from previous step

    {
      const int kb = sh16;
      As[(kb + 0) * LDW + scol] = (av0.x * wv0.x) * sA;
      As[(kb + 1) * LDW + scol] = (av0.y * wv0.y) * sA;
      As[(kb + 2) * LDW + scol] = (av0.z * wv0.z) * sA;
      As[(kb + 3) * LDW + scol] = (av0.w * wv0.w) * sA;
      As[(kb + 4) * LDW + scol] = (av1.x * wv1.x) * sA;
      As[(kb + 5) * LDW + scol] = (av1.y * wv1.y) * sA;
      As[(kb + 6) * LDW + scol] = (av1.z * wv1.z) * sA;
      As[(kb + 7) * LDW + scol] = (av1.w * wv1.w) * sA;
      Bs[(kb + 0) * LDW + scol] = (bv0.x * wv0.x) * sB;
      Bs[(kb + 1) * LDW + scol] = (bv0.y * wv0.y) * sB;
      Bs[(kb + 2) * LDW + scol] = (bv0.z * wv0.z) * sB;
      Bs[(kb + 3) * LDW + scol] = (bv0.w * wv0.w) * sB;
      Bs[(kb + 4) * LDW + scol] = (bv1.x * wv1.x) * sB;
      Bs[(kb + 5) * LDW + scol] = (bv1.y * wv1.y) * sB;
      Bs[(kb + 6) * LDW + scol] = (bv1.z * wv1.z) * sB;
      Bs[(kb + 7) * LDW + scol] = (bv1.w * wv1.w) * sB;
    }
    // second half-chunk (loads overlap the first chunk's LDS writes)
    {
      float4 wv2 = *reinterpret_cast<const float4*>(wrow + 8);
      float4 wv3 = *reinterpret_cast<const float4*>(wrow + 12);
      float4 av2 = *reinterpret_cast<const float4*>(arow + 8);
      float4 av3 = *reinterpret_cast<const float4*>(arow + 12);
      float4 bv2 = *reinterpret_cast<const float4*>(brow + 8);
      float4 bv3 = *reinterpret_cast<const float4*>(brow + 12);
      const int kb = sh16 + 8;
      As[(kb + 0) * LDW + scol] = (av2.x * wv2.x) * sA;
      As[(kb + 1) * LDW + scol] = (av2.y * wv2.y) * sA;
      As[(kb + 2) * LDW + scol] = (av2.z * wv2.z) * sA;
      As[(kb + 3) * LDW + scol] = (av2.w * wv2.w) * sA;
      As[(kb + 4) * LDW + scol] = (av3.x * wv3.x) * sA;
      As[(kb + 5) * LDW + scol] = (av3.y * wv3.y) * sA;
      As[(kb + 6) * LDW + scol] = (av3.z * wv3.z) * sA;
      As[(kb + 7) * LDW + scol] = (av3.w * wv3.w) * sA;
      Bs[(kb + 0) * LDW + scol] = (bv2.x * wv2.x) * sB;
      Bs[(kb + 1) * LDW + scol] = (bv2.y * wv2.y) * sB;
      Bs[(kb + 2) * LDW + scol] = (bv2.z * wv2.z) * sB;
      Bs[(kb + 3) * LDW + scol] = (bv2.w * wv2.w) * sB;
      Bs[(kb + 4) * LDW + scol] = (bv3.x * wv3.x) * sB;
      Bs[(kb + 5) * LDW + scol] = (bv3.y * wv3.y) * sB;
      Bs[(kb + 6) * LDW + scol] = (bv3.z * wv3.z) * sB;
      Bs[(kb + 7) * LDW + scol] = (bv3.w * wv3.w) * sB;
    }

    __syncthreads();   // staged data visible

#pragma unroll
    for (int kk = 0; kk < KC; ++kk) {
      const float* arow_l = &As[kk * LDW];
      const float* brow_l = &Bs[kk * LDW];
      const float4 a0 = *reinterpret_cast<const float4*>(arow_l + aoff);
      const float4 a1 = *reinterpret_cast<const float4*>(arow_l + aoff + 4);
      const float4 b0 = *reinterpret_cast<const float4*>(brow_l + boff);
      const float4 b1 = *reinterpret_cast<const float4*>(brow_l + boff + 4);
      const float av[8] = {a0.x, a0.y, a0.z, a0.w, a1.x, a1.y, a1.z, a1.w};
      const float bv[8] = {b0.x, b0.y, b0.z, b0.w, b1.x, b1.y, b1.z, b1.w};
#pragma unroll
      for (int i = 0; i < 8; ++i)
#pragma unroll
        for (int j = 0; j < 8; ++j) acc[i][j] = fmaf(av[i], bv[j], acc[i][j]);
    }
  }

  // epilogue: straight tile + mirrored tile (unchanged)
#pragma unroll
  for (int i = 0; i < 8; ++i) {
    size_t base = (size_t)(Ro + ty8 + i) * N_CTX + Co + tx8;
    *reinterpret_cast<float4*>(out + base) =
        make_float4(acc[i][0], acc[i][1], acc[i][2], acc[i][3]);
    *reinterpret_cast<float4*>(out + base + 4) =
        make_float4(acc[i][4], acc[i][5], acc[i][6], acc[i][7]);
  }
  if (bx != by) {
#pragma unroll
    for (int j = 0; j < 8; ++j) {
      size_t base = (size_t)(Co + tx8 + j) * N_CTX + Ro + ty8;
      *reinterpret_cast<float4*>(out + base) =
          make_float4(acc[0][j], acc[1][j], acc[2][j], acc[3][j]);
      *reinterpret_cast<float4*>(out + base + 4) =
          make_float4(acc[4][j], acc[5][j], acc[6][j], acc[7][j]);
    }
  }
}

// ---------------------------------------------------------------------------
// Kernel 3: per-row epsilon threshold + exact top-30 mask. UNCHANGED.
// ---------------------------------------------------------------------------
__global__ __launch_bounds__(256) void topk_kernel(float* __restrict__ att) {
  __shared__ unsigned red[4];
  __shared__ unsigned eqcnt[256];

  const int n = blockIdx.x;
  const int t = threadIdx.x;
  const int wid = t >> 6, lane = t & 63;
  float* row = att + (size_t)n * N_CTX;

  float vr[16];
  unsigned ur[16];
#pragma unroll
  for (int i = 0; i < 4; ++i) {
    float4 v4 = *reinterpret_cast<const float4*>(row + t * 16 + i * 4);
    float tmp[4] = {v4.x, v4.y, v4.z, v4.w};
#pragma unroll
    for (int j = 0; j < 4; ++j) {
      float v = tmp[j];
      v = (v > EPS_NN) ? v : 0.0f;
      vr[i * 4 + j] = v;
      ur[i * 4 + j] = __float_as_uint(v);
    }
  }

  unsigned lo = 0u, hi = 0x7F800000u;
  while (lo < hi) {
    unsigned mid = lo + ((hi - lo) >> 1);
    unsigned c = 0;
#pragma unroll
    for (int i = 0; i < 16; ++i) c += (ur[i] > mid) ? 1u : 0u;
#pragma unroll
    for (int off = 32; off; off >>= 1) c += __shfl_down(c, off, 64);
    if (lane == 0) red[wid] = c;
    __syncthreads();
    unsigned tot = red[0] + red[1] + red[2] + red[3];
    __syncthreads();
    if (tot < TOPK_K) hi = mid; else lo = mid + 1;
  }
  const unsigned kbits = lo;

  {
    unsigned c = 0;
#pragma unroll
    for (int i = 0; i < 16; ++i) c += (ur[i] > kbits) ? 1u : 0u;
#pragma unroll
    for (int off = 32; off; off >>= 1) c += __shfl_down(c, off, 64);
    if (lane == 0) red[wid] = c;
  }
  __syncthreads();
  const unsigned gt = red[0] + red[1] + red[2] + red[3];
  const unsigned r_eq = TOPK_K - gt;
  __syncthreads();

  unsigned ec = 0;
#pragma unroll
  for (int i = 0; i < 16; ++i) ec += (ur[i] == kbits) ? 1u : 0u;
  eqcnt[t] = ec;
  __syncthreads();
  for (int off = 1; off < 256; off <<= 1) {
    unsigned v = eqcnt[t];
    unsigned add = (t >= off) ? eqcnt[t - off] : 0u;
    __syncthreads();
    eqcnt[t] = v + add;
    __syncthreads();
  }
  const unsigned prefix = eqcnt[t] - ec;

  unsigned seen = 0;
#pragma unroll
  for (int i = 0; i < 16; ++i) {
    float o = 0.0f;
    if (ur[i] > kbits) {
      o = vr[i];
    } else if (kbits != 0u && ur[i] == kbits) {
      if (prefix + seen < r_eq) o = vr[i];
      ++seen;
    }
    vr[i] = o;
  }
#pragma unroll
  for (int i = 0; i < 4; ++i) {
    *reinterpret_cast<float4*>(row + t * 16 + i * 4) =
        make_float4(vr[i * 4], vr[i * 4 + 1], vr[i * 4 + 2], vr[i * 4 + 3]);
  }
}

// ---------------------------------------------------------------------------
extern "C" void kernel_launch(void* const* d_in, const int* in_sizes, int n_in,
                              void* d_out, int out_size, void* d_ws, size_t ws_size,
                              hipStream_t stream) {
  const float* ctx = (const float*)d_in[0];   // (4096, 512)
  const float* w   = (const float*)d_in[1];   // (16, 512)
  float* out = (float*)d_out;                 // (4096, 4096)
  float* invr = (float*)d_ws;                 // 16*4096 f32 = 256 KB scratch

  norms_kernel<<<(NPERS * N_CTX) / 4, 256, 0, stream>>>(ctx, w, invr);

  att_gemm<<<528, 256, 0, stream>>>(ctx, w, invr, out);   // triangular grid

  topk_kernel<<<N_CTX, 256, 0, stream>>>(out);
}